// Round 11
// baseline (202.018 us; speedup 1.0000x reference)
//
#include <hip/hip_runtime.h>

typedef __bf16 bf16x8 __attribute__((ext_vector_type(8)));
typedef float f32x4 __attribute__((ext_vector_type(4)));
typedef unsigned short u16;
typedef u16 u16x8 __attribute__((ext_vector_type(8)));
typedef u16 u16x2 __attribute__((ext_vector_type(2)));

__device__ __forceinline__ u16 f2bf(float f) {
    union { float f; unsigned u; } x; x.f = f;
    unsigned r = x.u + 0x7fffu + ((x.u >> 16) & 1u);
    return (u16)(r >> 16);
}
__device__ __forceinline__ float bf2f(u16 v) {
    union { unsigned u; float f; } x; x.u = ((unsigned)v) << 16;
    return x.f;
}
__device__ __forceinline__ bf16x8 as_bf16x8(u16x8 v) {
    return __builtin_bit_cast(bf16x8, v);
}
__device__ __forceinline__ void glds16(const void* g, void* l) {
    __builtin_amdgcn_global_load_lds(
        (const __attribute__((address_space(1))) void*)g,
        (__attribute__((address_space(3))) void*)l, 16, 0, 0);
}

// fp32 -> bf16, 8 elems/thread
__global__ __launch_bounds__(256) void f32bf16(const float* __restrict__ in,
                                               u16* __restrict__ out, int n8) {
    int i = blockIdx.x * 256 + threadIdx.x;
    if (i >= n8) return;
    const float4* p = (const float4*)(in + (size_t)i * 8);
    float4 a = p[0], b = p[1];
    u16x8 o;
    o[0] = f2bf(a.x); o[1] = f2bf(a.y); o[2] = f2bf(a.z); o[3] = f2bf(a.w);
    o[4] = f2bf(b.x); o[5] = f2bf(b.y); o[6] = f2bf(b.z); o[7] = f2bf(b.w);
    *(u16x8*)(out + (size_t)i * 8) = o;
}

// C[m][n] = sum_k A[m][k]*B[n][k]; A,B bf16 row-major; C fp32 or bf16 (template).
// 128x128 tile, 4 waves, BK=32, global_load_lds + 2-phase dbuf. 1-D grid,
// XCD-bijective swizzle (grid % 8 == 0), col tiles = nbx.
template<bool BF16OUT>
__global__ __launch_bounds__(256) void gemm128(const u16* __restrict__ A,
                                               const u16* __restrict__ B,
                                               void* __restrict__ Cv,
                                               int N, int K, int nbx) {
    __shared__ u16 As[2][4096];   // [128][32] linear, matches gload_lds lane order
    __shared__ u16 Bs[2][4096];
    const int tid = threadIdx.x, lane = tid & 63, wave = tid >> 6;
    const int cpx = gridDim.x >> 3;
    const int nid = (blockIdx.x & 7) * cpx + (blockIdx.x >> 3);
    const int m0 = (nid / nbx) << 7, n0 = (nid % nbx) << 7;
    const int wr = (wave >> 1) << 6, wc = (wave & 1) << 6;
    const int fr = lane & 15, fo = (lane >> 4) << 3;
    const int srow = tid >> 2, scol = (tid & 3) << 3;
    const u16* Ag = A + (size_t)(m0 + srow) * K + scol;
    const u16* Bg = B + (size_t)(n0 + srow) * K + scol;
    u16* AsW = &As[0][0] + (wave << 9);   // wave-uniform LDS base (+lane*16B by HW)
    u16* BsW = &Bs[0][0] + (wave << 9);
    f32x4 acc[4][4] = {};
    const int nsteps = K >> 5;
    glds16(Ag, AsW);
    glds16(Ag + (size_t)64 * K, AsW + 2048);
    glds16(Bg, BsW);
    glds16(Bg + (size_t)64 * K, BsW + 2048);
    int cur = 0;
    for (int s = 0; s < nsteps; ++s) {
        __syncthreads();   // buf[cur] staged (drains vmcnt), prev reads done
        if (s + 1 < nsteps) {
            const u16* Ap = Ag + (s + 1) * 32;
            const u16* Bp = Bg + (s + 1) * 32;
            const int nb = (cur ^ 1) << 12;
            glds16(Ap, AsW + nb);
            glds16(Ap + (size_t)64 * K, AsW + nb + 2048);
            glds16(Bp, BsW + nb);
            glds16(Bp + (size_t)64 * K, BsW + nb + 2048);
        }
        const u16* Ab = &As[cur][0];
        const u16* Bb = &Bs[cur][0];
        bf16x8 af[4], bfr[4];
        #pragma unroll
        for (int i = 0; i < 4; ++i)
            af[i] = *(const bf16x8*)(Ab + (wr + i * 16 + fr) * 32 + fo);
        #pragma unroll
        for (int i = 0; i < 4; ++i)
            bfr[i] = *(const bf16x8*)(Bb + (wc + i * 16 + fr) * 32 + fo);
        #pragma unroll
        for (int i = 0; i < 4; ++i)
            #pragma unroll
            for (int j = 0; j < 4; ++j)
                acc[i][j] = __builtin_amdgcn_mfma_f32_16x16x32_bf16(af[i], bfr[j], acc[i][j], 0, 0, 0);
        cur ^= 1;
    }
    const int cr = (lane >> 4) << 2, cc = lane & 15;
    if constexpr (BF16OUT) {
        u16* C = (u16*)Cv;
        #pragma unroll
        for (int i = 0; i < 4; ++i)
            for (int j = 0; j < 4; ++j)
                for (int r = 0; r < 4; ++r)
                    C[(size_t)(m0 + wr + i * 16 + cr + r) * N + (n0 + wc + j * 16 + cc)] =
                        f2bf(acc[i][j][r]);
    } else {
        float* C = (float*)Cv;
        #pragma unroll
        for (int i = 0; i < 4; ++i)
            for (int j = 0; j < 4; ++j)
                for (int r = 0; r < 4; ++r)
                    C[(size_t)(m0 + wr + i * 16 + cr + r) * N + (n0 + wc + j * 16 + cc)] =
                        acc[i][j][r];
    }
}

// qkv bf16 [B*S][3072] -> RoPE'd Q (pre-scaled by 0.125*log2(e)), K bf16 [b,h,s,64].
__global__ __launch_bounds__(256) void rope_split(const u16* __restrict__ qkv,
                                                  const int* __restrict__ pos,
                                                  u16* __restrict__ Qb,
                                                  u16* __restrict__ Kb) {
    int tid = blockIdx.x * 256 + threadIdx.x;   // 0 .. 2^21-1
    int t = tid & 31;
    int h = (tid >> 5) & 15;
    int s = (tid >> 9) & 2047;
    int b = tid >> 20;
    const u16* row = qkv + (size_t)((b << 11) + s) * 3072;
    float fp  = (float)pos[s];
    float inv = exp2f((float)t * -0.4152410118609203f);
    float rev = fp * inv * 0.15915494309189535f;
    rev = rev - floorf(rev);
    float sn = __builtin_amdgcn_sinf(rev);   // v_sin_f32: sin(2*pi*x)
    float cs = __builtin_amdgcn_cosf(rev);
    int off = h * 64 + 2 * t;
    u16x2 q2 = *(const u16x2*)(row + off);
    u16x2 k2 = *(const u16x2*)(row + 1024 + off);
    float qx = bf2f(q2[0]), qy = bf2f(q2[1]);
    float kx = bf2f(k2[0]), ky = bf2f(k2[1]);
    size_t oidx = (((size_t)(b * 16 + h) * 2048) + s) * 64 + 2 * t;
    const float qs = 0.18033688011112042f;   // 0.125 * log2(e)
    u16x2 qo, ko;
    qo[0] = f2bf((qx * cs - qy * sn) * qs);
    qo[1] = f2bf((qx * sn + qy * cs) * qs);
    ko[0] = f2bf(kx * cs - ky * sn);
    ko[1] = f2bf(ky * cs + kx * sn);
    *(u16x2*)&Qb[oidx] = qo;
    *(u16x2*)&Kb[oidx] = ko;
}

// V-part of qkv (bf16) -> transposed Vt[b,h,d][tile*64 + p] where storage pos p
// holds actual key k(p) = 32*(p>>5) + 4*((p>>3)&3) + (p&3) + 16*((p>>2)&1)
// (the PV A/B-operand k-permutation for the in-register-P swapped-QK scheme).
__global__ __launch_bounds__(256) void vtrans(const u16* __restrict__ qkv,
                                              u16* __restrict__ Vt) {
    __shared__ u16 lds[64][72];
    const int t = threadIdx.x;
    const int st = blockIdx.x, h = blockIdx.y, b = blockIdx.z;
    const int s0 = st << 6;
    {
        const int r = t >> 2, c0 = (t & 3) << 4;
        const u16* src = qkv + (size_t)((b << 11) + s0 + r) * 3072 + 2048 + h * 64 + c0;
        *(u16x8*)&lds[r][c0]     = *(const u16x8*)src;
        *(u16x8*)&lds[r][c0 + 8] = *(const u16x8*)(src + 8);
    }
    __syncthreads();
    const size_t obase = ((size_t)((b << 4) + h) << 17) + (st << 6);
    #pragma unroll
    for (int w = 0; w < 2; ++w) {
        const int q = t + (w << 8);
        const int d = q >> 3, c = q & 7;
        u16x8 o;
        #pragma unroll
        for (int i = 0; i < 8; ++i) {
            const int p = (c << 3) + i;          // storage position 0..63
            const int k = ((p >> 5) << 5) + (((p >> 3) & 3) << 2) + (p & 3)
                        + (((p >> 2) & 1) << 4); // actual key
            o[i] = lds[k][d];
        }
        *(u16x8*)(Vt + obase + ((size_t)d << 11) + (c << 3)) = o;
    }
}

// Causal flash attention, NO online max, IN-REGISTER P, NO K/V LDS STAGING.
// K/V are L2-resident (XCD swizzle pins 4 groups/XCD) -> direct global->reg
// reads; no per-tile barrier; each wave runs its 33-tile loop independently.
// K pipelined 1 tile ahead (named ping/pong reg sets); V issued at tile start,
// consumed after QK+exp (~200cyc) -> latency covered by L1/L2.
// 512 blocks x 8 waves; block = balanced pair (qt, 31-pr). Wave (qsub,half):
// 16 q-rows x 32 keys. Combine via dedicated LDS buffer (r9/r10 epilogue).
__global__ __launch_bounds__(512, 4) void attn_causal(const u16* __restrict__ Q,
                                                      const u16* __restrict__ K,
                                                      const u16* __restrict__ Vt,
                                                      u16* __restrict__ O) {
    __shared__ float cmb[5120];  // combine slots: [qsub][lane][20]
    const int tid = threadIdx.x, lane = tid & 63, wave = tid >> 6;
    const int nid = ((blockIdx.x & 7) << 6) + (blockIdx.x >> 3);   // XCD-contiguous
    const int pr = nid & 15, h = (nid >> 4) & 15, b = nid >> 8;
    const int S = 2048;
    const size_t base = (size_t)((b << 4) + h) << 17;   // (b*16+h)*2048*64
    const int fr = lane & 15, fo = (lane >> 4) << 3, cr = (lane >> 4) << 2;
    const int qsub = wave >> 1, half = wave & 1;
    float* const slot = cmb + qsub * 1280 + lane * 20;
    u16x8 ones_u;
    #pragma unroll
    for (int i = 0; i < 8; ++i) ones_u[i] = 0x3F80;   // bf16 1.0
    const bf16x8 ones = as_bf16x8(ones_u);

    // per-lane global base pointers (advance by t at use sites)
    // K chunk ch: row (2*half+ch)*16+fr, cols fo / fo+32; tile stride 4096 elems
    const u16* const Kp0 = K + base + (size_t)(((half << 1) + 0) * 16 + fr) * 64 + fo;
    const u16* const Kp1 = K + base + (size_t)(((half << 1) + 1) * 16 + fr) * 64 + fo;
    // V row d = tt*16+fr, col half*32+fo; tile stride 64 elems
    const u16* const Vp0 = Vt + base + (size_t)(0 * 16 + fr) * 2048 + (half << 5) + fo;
    const u16* const Vp1 = Vt + base + (size_t)(1 * 16 + fr) * 2048 + (half << 5) + fo;
    const u16* const Vp2 = Vt + base + (size_t)(2 * 16 + fr) * 2048 + (half << 5) + fo;
    const u16* const Vp3 = Vt + base + (size_t)(3 * 16 + fr) * 2048 + (half << 5) + fo;

    for (int phase = 0; phase < 2; ++phase) {
        const int qt = phase ? (31 - pr) : pr;
        const int nkt = qt + 1;
        const int qw = (qt << 6) + (qsub << 4);
        bf16x8 aq0, aq1;
        {
            const u16* qrow = Q + base + (size_t)(qw + fr) * 64;
            aq0 = as_bf16x8(*(const u16x8*)(qrow + fo));
            aq1 = as_bf16x8(*(const u16x8*)(qrow + 32 + fo));
        }
        f32x4 oacc[4] = {};
        f32x4 lacc = {};
        const int qloc = (qsub << 4) + fr;

        auto loadK = [&](int t, u16x8& a, u16x8& b, u16x8& c, u16x8& d) {
            const size_t to = (size_t)t << 12;
            a = *(const u16x8*)(Kp0 + to);
            b = *(const u16x8*)(Kp0 + to + 32);
            c = *(const u16x8*)(Kp1 + to);
            d = *(const u16x8*)(Kp1 + to + 32);
        };
        auto tile = [&](int t, u16x8 k00, u16x8 k01, u16x8 k10, u16x8 k11) {
            const bool diag = (t == nkt - 1);
            const size_t vo = (size_t)t << 6;
            u16x8 v0 = *(const u16x8*)(Vp0 + vo);
            u16x8 v1 = *(const u16x8*)(Vp1 + vo);
            u16x8 v2 = *(const u16x8*)(Vp2 + vo);
            u16x8 v3 = *(const u16x8*)(Vp3 + vo);
            // swapped QK^T: lane holds 8 scores for q=fr at k=16*cglob+cr+reg
            f32x4 s0 = {}, s1 = {};
            s0 = __builtin_amdgcn_mfma_f32_16x16x32_bf16(as_bf16x8(k00), aq0, s0, 0, 0, 0);
            s0 = __builtin_amdgcn_mfma_f32_16x16x32_bf16(as_bf16x8(k01), aq1, s0, 0, 0, 0);
            s1 = __builtin_amdgcn_mfma_f32_16x16x32_bf16(as_bf16x8(k10), aq0, s1, 0, 0, 0);
            s1 = __builtin_amdgcn_mfma_f32_16x16x32_bf16(as_bf16x8(k11), aq1, s1, 0, 0, 0);
            // exp2 -> in-register PV A-fragment (mask = value-select on diag)
            bf16x8 pa;
            #pragma unroll
            for (int r = 0; r < 4; ++r) {
                float e0 = exp2f(s0[r]);
                float e1 = exp2f(s1[r]);
                if (diag) {
                    const int k0l = ((half << 1) << 4) + cr + r;
                    const int k1l = k0l + 16;
                    e0 = (k0l <= qloc) ? e0 : 0.f;
                    e1 = (k1l <= qloc) ? e1 : 0.f;
                }
                pa[r]     = (__bf16)e0;
                pa[4 + r] = (__bf16)e1;
            }
            // PV + row-sum (ones-MFMA)
            lacc = __builtin_amdgcn_mfma_f32_16x16x32_bf16(pa, ones, lacc, 0, 0, 0);
            oacc[0] = __builtin_amdgcn_mfma_f32_16x16x32_bf16(pa, as_bf16x8(v0), oacc[0], 0, 0, 0);
            oacc[1] = __builtin_amdgcn_mfma_f32_16x16x32_bf16(pa, as_bf16x8(v1), oacc[1], 0, 0, 0);
            oacc[2] = __builtin_amdgcn_mfma_f32_16x16x32_bf16(pa, as_bf16x8(v2), oacc[2], 0, 0, 0);
            oacc[3] = __builtin_amdgcn_mfma_f32_16x16x32_bf16(pa, as_bf16x8(v3), oacc[3], 0, 0, 0);
        };

        u16x8 a0, a1, a2, a3, b0, b1, b2, b3;   // named ping/pong K sets
        loadK(0, a0, a1, a2, a3);
        for (int t = 0; t < nkt; t += 2) {
            if (t + 1 < nkt) loadK(t + 1, b0, b1, b2, b3);
            tile(t, a0, a1, a2, a3);
            if (t + 1 >= nkt) break;
            if (t + 2 < nkt) loadK(t + 2, a0, a1, a2, a3);
            tile(t + 1, b0, b1, b2, b3);
        }

        // ---- combine halves (additive) via dedicated buffer + store ----
        __syncthreads();
        if (half) {
            #pragma unroll
            for (int tt = 0; tt < 4; ++tt) *(f32x4*)(slot + tt * 4) = oacc[tt];
            *(f32x4*)(slot + 16) = lacc;
        }
        __syncthreads();
        if (!half) {
            #pragma unroll
            for (int tt = 0; tt < 4; ++tt) oacc[tt] += *(const f32x4*)(slot + tt * 4);
            lacc += *(const f32x4*)(slot + 16);
            f32x4 inv;
            #pragma unroll
            for (int j = 0; j < 4; ++j) inv[j] = 1.f / lacc[j];
            #pragma unroll
            for (int tt = 0; tt < 4; ++tt)
                for (int j = 0; j < 4; ++j)
                    O[(size_t)(b * S + qw + cr + j) * 1024 + h * 64 + tt * 16 + fr] =
                        f2bf(oacc[tt][j] * inv[j]);
        }
        __syncthreads();
    }
}

extern "C" void kernel_launch(void* const* d_in, const int* in_sizes, int n_in,
                              void* d_out, int out_size, void* d_ws, size_t ws_size,
                              hipStream_t stream) {
    const float* x     = (const float*)d_in[0];   // [2,2048,1024]
    const float* qkv_w = (const float*)d_in[1];   // [3072,1024]
    const float* out_w = (const float*)d_in[2];   // [1024,1024]
    const int*   pos   = (const int*)d_in[3];     // [2048]
    float* out = (float*)d_out;                   // [2,2048,1024] fp32

    char* ws = (char*)d_ws;
    u16* qkv16 = (u16*)ws;                           // 4096*3072*2 = 25165824 B
    u16* Qb    = (u16*)(ws + 25165824);              // 8388608 B
    u16* Kb    = (u16*)(ws + 33554432);              // 8388608 B
    u16* Vtg   = (u16*)(ws + 41943040);              // 8388608 B (transposed V)
    u16* x16   = (u16*)(ws + 50331648);              // 8388608 B (reused as att16)
    u16* att16 = (u16*)(ws + 50331648);
    u16* w16   = (u16*)(ws + 58720256);              // 6291456 B
    u16* ow16  = (u16*)(ws + 65011712);              // 2097152 B  (total 67108864)

    // 0) fp32 -> bf16 converts
    f32bf16<<<2048, 256, 0, stream>>>(x, x16, 524288);
    f32bf16<<<1536, 256, 0, stream>>>(qkv_w, w16, 393216);
    f32bf16<<<512, 256, 0, stream>>>(out_w, ow16, 131072);
    // 1) qkv16 = x @ qkv_w^T (bf16 out): M=4096, N=3072, K=1024
    gemm128<true><<<768, 256, 0, stream>>>(x16, w16, (void*)qkv16, 3072, 1024, 24);
    // 2a) RoPE Q,K (Q pre-scaled by 0.125*log2e), fast trig
    rope_split<<<8192, 256, 0, stream>>>(qkv16, pos, Qb, Kb);
    // 2b) V transpose + PV-operand k-perm -> Vtg
    vtrans<<<dim3(32, 16, 2), 256, 0, stream>>>(qkv16, Vtg);
    // 3) causal flash attention: 512 blocks x 512 thr, balanced pairs, no K/V LDS
    attn_causal<<<512, 512, 0, stream>>>(Qb, Kb, Vtg, att16);
    // 4) out = att16 @ out_w^T (fp32 out): M=4096, N=1024, K=1024
    gemm128<false><<<256, 256, 0, stream>>>(att16, ow16, (void*)out, 1024, 1024, 8);
}

// Round 12
// 121.922 us; speedup vs baseline: 1.6570x; 1.6570x over previous
//
#include <hip/hip_runtime.h>

typedef __bf16 bf16x8 __attribute__((ext_vector_type(8)));
typedef float f32x4 __attribute__((ext_vector_type(4)));
typedef unsigned short u16;
typedef u16 u16x8 __attribute__((ext_vector_type(8)));
typedef u16 u16x2 __attribute__((ext_vector_type(2)));

__device__ __forceinline__ u16 f2bf(float f) {
    union { float f; unsigned u; } x; x.f = f;
    unsigned r = x.u + 0x7fffu + ((x.u >> 16) & 1u);
    return (u16)(r >> 16);
}
__device__ __forceinline__ float bf2f(u16 v) {
    union { unsigned u; float f; } x; x.u = ((unsigned)v) << 16;
    return x.f;
}
__device__ __forceinline__ bf16x8 as_bf16x8(u16x8 v) {
    return __builtin_bit_cast(bf16x8, v);
}
__device__ __forceinline__ void glds16(const void* g, void* l) {
    __builtin_amdgcn_global_load_lds(
        (const __attribute__((address_space(1))) void*)g,
        (__attribute__((address_space(3))) void*)l, 16, 0, 0);
}
// row swizzle in u16-chunk units for 64-u16 rows: s8(r)=(r&7)^((r>>3)&7)
__device__ __forceinline__ int swz(int r) { return (((r & 7) ^ ((r >> 3) & 7)) << 3); }

// fp32 -> bf16, 8 elems/thread
__global__ __launch_bounds__(256) void f32bf16(const float* __restrict__ in,
                                               u16* __restrict__ out, int n8) {
    int i = blockIdx.x * 256 + threadIdx.x;
    if (i >= n8) return;
    const float4* p = (const float4*)(in + (size_t)i * 8);
    float4 a = p[0], b = p[1];
    u16x8 o;
    o[0] = f2bf(a.x); o[1] = f2bf(a.y); o[2] = f2bf(a.z); o[3] = f2bf(a.w);
    o[4] = f2bf(b.x); o[5] = f2bf(b.y); o[6] = f2bf(b.z); o[7] = f2bf(b.w);
    *(u16x8*)(out + (size_t)i * 8) = o;
}

// C[m][n] = sum_k A[m][k]*B[n][k]; A,B bf16 row-major; C fp32 or bf16 (template).
// 128x128 tile, 4 waves, BK=32, global_load_lds + 2-phase dbuf. 1-D grid,
// XCD-bijective swizzle (grid % 8 == 0), col tiles = nbx.
template<bool BF16OUT>
__global__ __launch_bounds__(256) void gemm128(const u16* __restrict__ A,
                                               const u16* __restrict__ B,
                                               void* __restrict__ Cv,
                                               int N, int K, int nbx) {
    __shared__ u16 As[2][4096];   // [128][32] linear, matches gload_lds lane order
    __shared__ u16 Bs[2][4096];
    const int tid = threadIdx.x, lane = tid & 63, wave = tid >> 6;
    const int cpx = gridDim.x >> 3;
    const int nid = (blockIdx.x & 7) * cpx + (blockIdx.x >> 3);
    const int m0 = (nid / nbx) << 7, n0 = (nid % nbx) << 7;
    const int wr = (wave >> 1) << 6, wc = (wave & 1) << 6;
    const int fr = lane & 15, fo = (lane >> 4) << 3;
    const int srow = tid >> 2, scol = (tid & 3) << 3;
    const u16* Ag = A + (size_t)(m0 + srow) * K + scol;
    const u16* Bg = B + (size_t)(n0 + srow) * K + scol;
    u16* AsW = &As[0][0] + (wave << 9);   // wave-uniform LDS base (+lane*16B by HW)
    u16* BsW = &Bs[0][0] + (wave << 9);
    f32x4 acc[4][4] = {};
    const int nsteps = K >> 5;
    glds16(Ag, AsW);
    glds16(Ag + (size_t)64 * K, AsW + 2048);
    glds16(Bg, BsW);
    glds16(Bg + (size_t)64 * K, BsW + 2048);
    int cur = 0;
    for (int s = 0; s < nsteps; ++s) {
        __syncthreads();   // buf[cur] staged (drains vmcnt), prev reads done
        if (s + 1 < nsteps) {
            const u16* Ap = Ag + (s + 1) * 32;
            const u16* Bp = Bg + (s + 1) * 32;
            const int nb = (cur ^ 1) << 12;
            glds16(Ap, AsW + nb);
            glds16(Ap + (size_t)64 * K, AsW + nb + 2048);
            glds16(Bp, BsW + nb);
            glds16(Bp + (size_t)64 * K, BsW + nb + 2048);
        }
        const u16* Ab = &As[cur][0];
        const u16* Bb = &Bs[cur][0];
        bf16x8 af[4], bfr[4];
        #pragma unroll
        for (int i = 0; i < 4; ++i)
            af[i] = *(const bf16x8*)(Ab + (wr + i * 16 + fr) * 32 + fo);
        #pragma unroll
        for (int i = 0; i < 4; ++i)
            bfr[i] = *(const bf16x8*)(Bb + (wc + i * 16 + fr) * 32 + fo);
        #pragma unroll
        for (int i = 0; i < 4; ++i)
            #pragma unroll
            for (int j = 0; j < 4; ++j)
                acc[i][j] = __builtin_amdgcn_mfma_f32_16x16x32_bf16(af[i], bfr[j], acc[i][j], 0, 0, 0);
        cur ^= 1;
    }
    const int cr = (lane >> 4) << 2, cc = lane & 15;
    if constexpr (BF16OUT) {
        u16* C = (u16*)Cv;
        #pragma unroll
        for (int i = 0; i < 4; ++i)
            for (int j = 0; j < 4; ++j)
                for (int r = 0; r < 4; ++r)
                    C[(size_t)(m0 + wr + i * 16 + cr + r) * N + (n0 + wc + j * 16 + cc)] =
                        f2bf(acc[i][j][r]);
    } else {
        float* C = (float*)Cv;
        #pragma unroll
        for (int i = 0; i < 4; ++i)
            for (int j = 0; j < 4; ++j)
                for (int r = 0; r < 4; ++r)
                    C[(size_t)(m0 + wr + i * 16 + cr + r) * N + (n0 + wc + j * 16 + cc)] =
                        acc[i][j][r];
    }
}

// qkv bf16 [B*S][3072] -> RoPE'd Q (pre-scaled by 0.125*log2(e)), K bf16 [b,h,s,64].
__global__ __launch_bounds__(256) void rope_split(const u16* __restrict__ qkv,
                                                  const int* __restrict__ pos,
                                                  u16* __restrict__ Qb,
                                                  u16* __restrict__ Kb) {
    int tid = blockIdx.x * 256 + threadIdx.x;   // 0 .. 2^21-1
    int t = tid & 31;
    int h = (tid >> 5) & 15;
    int s = (tid >> 9) & 2047;
    int b = tid >> 20;
    const u16* row = qkv + (size_t)((b << 11) + s) * 3072;
    float fp  = (float)pos[s];
    float inv = exp2f((float)t * -0.4152410118609203f);
    float rev = fp * inv * 0.15915494309189535f;
    rev = rev - floorf(rev);
    float sn = __builtin_amdgcn_sinf(rev);   // v_sin_f32: sin(2*pi*x)
    float cs = __builtin_amdgcn_cosf(rev);
    int off = h * 64 + 2 * t;
    u16x2 q2 = *(const u16x2*)(row + off);
    u16x2 k2 = *(const u16x2*)(row + 1024 + off);
    float qx = bf2f(q2[0]), qy = bf2f(q2[1]);
    float kx = bf2f(k2[0]), ky = bf2f(k2[1]);
    size_t oidx = (((size_t)(b * 16 + h) * 2048) + s) * 64 + 2 * t;
    const float qs = 0.18033688011112042f;   // 0.125 * log2(e)
    u16x2 qo, ko;
    qo[0] = f2bf((qx * cs - qy * sn) * qs);
    qo[1] = f2bf((qx * sn + qy * cs) * qs);
    ko[0] = f2bf(kx * cs - ky * sn);
    ko[1] = f2bf(ky * cs + kx * sn);
    *(u16x2*)&Qb[oidx] = qo;
    *(u16x2*)&Kb[oidx] = ko;
}

// V-part of qkv (bf16) -> transposed Vt[b,h,d][tile*64 + p] where storage pos p
// holds actual key k(p) = 32*(p>>5) + 4*((p>>3)&3) + (p&3) + 16*((p>>2)&1)
// (the PV A/B-operand k-permutation for the in-register-P swapped-QK scheme).
__global__ __launch_bounds__(256) void vtrans(const u16* __restrict__ qkv,
                                              u16* __restrict__ Vt) {
    __shared__ u16 lds[64][72];
    const int t = threadIdx.x;
    const int st = blockIdx.x, h = blockIdx.y, b = blockIdx.z;
    const int s0 = st << 6;
    {
        const int r = t >> 2, c0 = (t & 3) << 4;
        const u16* src = qkv + (size_t)((b << 11) + s0 + r) * 3072 + 2048 + h * 64 + c0;
        *(u16x8*)&lds[r][c0]     = *(const u16x8*)src;
        *(u16x8*)&lds[r][c0 + 8] = *(const u16x8*)(src + 8);
    }
    __syncthreads();
    const size_t obase = ((size_t)((b << 4) + h) << 17) + (st << 6);
    #pragma unroll
    for (int w = 0; w < 2; ++w) {
        const int q = t + (w << 8);
        const int d = q >> 3, c = q & 7;
        u16x8 o;
        #pragma unroll
        for (int i = 0; i < 8; ++i) {
            const int p = (c << 3) + i;          // storage position 0..63
            const int k = ((p >> 5) << 5) + (((p >> 3) & 3) << 2) + (p & 3)
                        + (((p >> 2) & 1) << 4); // actual key
            o[i] = lds[k][d];
        }
        *(u16x8*)(Vt + obase + ((size_t)d << 11) + (c << 3)) = o;
    }
}

// Causal flash attention, NO online max, IN-REGISTER P (swapped-operand QK^T),
// LDS staging with COUNTED vmcnt + raw s_barrier (T3/T4): 3 buffers, prefetch
// depth 2, never drain vmcnt to 0 in the main loop. 512 blocks x 8 waves;
// block = balanced pair (qt, 31-pr). Wave (qsub,half): 16 q-rows x 32 keys.
// Per-wave stage = 2 glds16 (1/8 of K-tile + 1/8 of Vt-tile) -> vmcnt(2) at
// tile t waits exactly tile t's loads while t+1's stay in flight.
__global__ __launch_bounds__(512, 4) void attn_causal(const u16* __restrict__ Q,
                                                      const u16* __restrict__ K,
                                                      const u16* __restrict__ Vt,
                                                      u16* __restrict__ O) {
    __shared__ u16 smem[24576];  // 3 bufs x (K 4096 | V 4096) u16 = 48 KB
    __shared__ float cmb[5120];  // combine slots: [qsub][lane][20]
    const int tid = threadIdx.x, lane = tid & 63, wave = tid >> 6;
    const int nid = ((blockIdx.x & 7) << 6) + (blockIdx.x >> 3);   // XCD-contiguous
    const int pr = nid & 15, h = (nid >> 4) & 15, b = nid >> 8;
    const int S = 2048;
    const size_t base = (size_t)((b << 4) + h) << 17;   // (b*16+h)*2048*64
    const int fr = lane & 15, fo = (lane >> 4) << 3, cr = (lane >> 4) << 2;
    const int schk = lane & 7, srow8 = lane >> 3;
    const int qsub = wave >> 1, half = wave & 1;
    float* const slot = cmb + qsub * 1280 + lane * 20;
    u16x8 ones_u;
    #pragma unroll
    for (int i = 0; i < 8; ++i) ones_u[i] = 0x3F80;   // bf16 1.0
    const bf16x8 ones = as_bf16x8(ones_u);

    // stage tile t into buf bi: 1 glds16 for K (8 rows) + 1 for Vt (8 d-rows),
    // source-swizzled global addresses, LDS linear (s8(r) = srow8 ^ wave)
    auto stage = [&](int t, int bi) {
        const int r  = (wave << 3) + srow8;
        const int ck = (schk ^ srow8 ^ wave) << 3;
        glds16(K  + base + ((size_t)((t << 6) + r) << 6) + ck,
               &smem[bi * 8192 + (wave << 9)]);
        glds16(Vt + base + ((size_t)r << 11) + (t << 6) + ck,
               &smem[bi * 8192 + 4096 + (wave << 9)]);
    };

    for (int phase = 0; phase < 2; ++phase) {
        const int qt = phase ? (31 - pr) : pr;
        const int nkt = qt + 1;
        const int qw = (qt << 6) + (qsub << 4);
        bf16x8 aq0, aq1;
        {
            const u16* qrow = Q + base + (size_t)(qw + fr) * 64;
            aq0 = as_bf16x8(*(const u16x8*)(qrow + fo));
            aq1 = as_bf16x8(*(const u16x8*)(qrow + 32 + fo));
        }
        f32x4 oacc[4] = {};
        f32x4 lacc = {};
        const int qloc = (qsub << 4) + fr;
        stage(0, 0);
        if (nkt > 1) stage(1, 1);
        int cur = 0;
        for (int t = 0; t < nkt; ++t) {
            // counted wait: newest 2 VMEM ops are tile t+1's stages (if any);
            // wait everything older (tile t's stages + any Q loads).
            if (t + 1 < nkt) asm volatile("s_waitcnt vmcnt(2)" ::: "memory");
            else             asm volatile("s_waitcnt vmcnt(0)" ::: "memory");
            __builtin_amdgcn_s_barrier();           // raw: no vmcnt drain
            __builtin_amdgcn_sched_barrier(0);      // pin: nothing crosses
            int nb = cur + 2; if (nb >= 3) nb -= 3;
            if (t + 2 < nkt) stage(t + 2, nb);
            const u16* Kb = smem + cur * 8192;
            const u16* Vb = smem + cur * 8192 + 4096;
            const bool diag = (t == nkt - 1);
            // swapped QK^T: lane holds 8 scores for q=fr at k=16*cglob+cr+reg
            f32x4 sacc[2];
            #pragma unroll
            for (int ch = 0; ch < 2; ++ch) {
                const int r = ((half << 1) + ch) * 16 + fr;
                const int sw = swz(r);
                bf16x8 bk0 = *(const bf16x8*)&Kb[r * 64 + (fo ^ sw)];
                bf16x8 bk1 = *(const bf16x8*)&Kb[r * 64 + ((32 + fo) ^ sw)];
                f32x4 sc = {};
                sc = __builtin_amdgcn_mfma_f32_16x16x32_bf16(bk0, aq0, sc, 0, 0, 0);
                sc = __builtin_amdgcn_mfma_f32_16x16x32_bf16(bk1, aq1, sc, 0, 0, 0);
                sacc[ch] = sc;
            }
            // exp2 -> in-register PV A-fragment (mask = value-select on diag)
            bf16x8 pa;
            #pragma unroll
            for (int ch = 0; ch < 2; ++ch) {
                const int cglob = (half << 1) + ch;
                #pragma unroll
                for (int r = 0; r < 4; ++r) {
                    float e = exp2f(sacc[ch][r]);
                    if (diag) {
                        const int kloc = (cglob << 4) + cr + r;
                        e = (kloc <= qloc) ? e : 0.f;
                    }
                    pa[ch * 4 + r] = (__bf16)e;
                }
            }
            // PV + row-sum (ones-MFMA)
            lacc = __builtin_amdgcn_mfma_f32_16x16x32_bf16(pa, ones, lacc, 0, 0, 0);
            #pragma unroll
            for (int tt = 0; tt < 4; ++tt) {
                const int d = tt * 16 + fr;
                bf16x8 bv = *(const bf16x8*)&Vb[d * 64 + (((half << 5) + fo) ^ swz(d))];
                oacc[tt] = __builtin_amdgcn_mfma_f32_16x16x32_bf16(pa, bv, oacc[tt], 0, 0, 0);
            }
            cur = (cur + 1 == 3) ? 0 : cur + 1;
        }
        // ---- combine halves (additive) via dedicated buffer + store ----
        __syncthreads();
        if (half) {
            #pragma unroll
            for (int tt = 0; tt < 4; ++tt) *(f32x4*)(slot + tt * 4) = oacc[tt];
            *(f32x4*)(slot + 16) = lacc;
        }
        __syncthreads();
        if (!half) {
            #pragma unroll
            for (int tt = 0; tt < 4; ++tt) oacc[tt] += *(const f32x4*)(slot + tt * 4);
            lacc += *(const f32x4*)(slot + 16);
            f32x4 inv;
            #pragma unroll
            for (int j = 0; j < 4; ++j) inv[j] = 1.f / lacc[j];
            #pragma unroll
            for (int tt = 0; tt < 4; ++tt)
                for (int j = 0; j < 4; ++j)
                    O[(size_t)(b * S + qw + cr + j) * 1024 + h * 64 + tt * 16 + fr] =
                        f2bf(oacc[tt][j] * inv[j]);
        }
        __syncthreads();
    }
}

extern "C" void kernel_launch(void* const* d_in, const int* in_sizes, int n_in,
                              void* d_out, int out_size, void* d_ws, size_t ws_size,
                              hipStream_t stream) {
    const float* x     = (const float*)d_in[0];   // [2,2048,1024]
    const float* qkv_w = (const float*)d_in[1];   // [3072,1024]
    const float* out_w = (const float*)d_in[2];   // [1024,1024]
    const int*   pos   = (const int*)d_in[3];     // [2048]
    float* out = (float*)d_out;                   // [2,2048,1024] fp32

    char* ws = (char*)d_ws;
    u16* qkv16 = (u16*)ws;                           // 4096*3072*2 = 25165824 B
    u16* Qb    = (u16*)(ws + 25165824);              // 8388608 B
    u16* Kb    = (u16*)(ws + 33554432);              // 8388608 B
    u16* Vtg   = (u16*)(ws + 41943040);              // 8388608 B (transposed V)
    u16* x16   = (u16*)(ws + 50331648);              // 8388608 B (reused as att16)
    u16* att16 = (u16*)(ws + 50331648);
    u16* w16   = (u16*)(ws + 58720256);              // 6291456 B
    u16* ow16  = (u16*)(ws + 65011712);              // 2097152 B  (total 67108864)

    // 0) fp32 -> bf16 converts
    f32bf16<<<2048, 256, 0, stream>>>(x, x16, 524288);
    f32bf16<<<1536, 256, 0, stream>>>(qkv_w, w16, 393216);
    f32bf16<<<512, 256, 0, stream>>>(out_w, ow16, 131072);
    // 1) qkv16 = x @ qkv_w^T (bf16 out): M=4096, N=3072, K=1024
    gemm128<true><<<768, 256, 0, stream>>>(x16, w16, (void*)qkv16, 3072, 1024, 24);
    // 2a) RoPE Q,K (Q pre-scaled by 0.125*log2e), fast trig
    rope_split<<<8192, 256, 0, stream>>>(qkv16, pos, Qb, Kb);
    // 2b) V transpose + PV-operand k-perm -> Vtg
    vtrans<<<dim3(32, 16, 2), 256, 0, stream>>>(qkv16, Vtg);
    // 3) causal flash attention: 512 blocks x 512 thr, counted-vmcnt pipeline
    attn_causal<<<512, 512, 0, stream>>>(Qb, Kb, Vtg, att16);
    // 4) out = att16 @ out_w^T (fp32 out): M=4096, N=1024, K=1024
    gemm128<false><<<256, 256, 0, stream>>>(att16, ow16, (void*)out, 1024, 1024, 8);
}

// Round 13
// 118.604 us; speedup vs baseline: 1.7033x; 1.0280x over previous
//
#include <hip/hip_runtime.h>

typedef __bf16 bf16x8 __attribute__((ext_vector_type(8)));
typedef float f32x4 __attribute__((ext_vector_type(4)));
typedef unsigned short u16;
typedef u16 u16x8 __attribute__((ext_vector_type(8)));
typedef u16 u16x2 __attribute__((ext_vector_type(2)));

__device__ __forceinline__ u16 f2bf(float f) {
    union { float f; unsigned u; } x; x.f = f;
    unsigned r = x.u + 0x7fffu + ((x.u >> 16) & 1u);
    return (u16)(r >> 16);
}
__device__ __forceinline__ float bf2f(u16 v) {
    union { unsigned u; float f; } x; x.u = ((unsigned)v) << 16;
    return x.f;
}
__device__ __forceinline__ bf16x8 as_bf16x8(u16x8 v) {
    return __builtin_bit_cast(bf16x8, v);
}
__device__ __forceinline__ void glds16(const void* g, void* l) {
    __builtin_amdgcn_global_load_lds(
        (const __attribute__((address_space(1))) void*)g,
        (__attribute__((address_space(3))) void*)l, 16, 0, 0);
}
// row swizzle in u16-chunk units for 64-u16 rows: s8(r)=(r&7)^((r>>3)&7)
__device__ __forceinline__ int swz(int r) { return (((r & 7) ^ ((r >> 3) & 7)) << 3); }

// fused fp32 -> bf16 for x (524288x8), qkv_w (393216x8), out_w (131072x8)
__global__ __launch_bounds__(256) void cvt3(const float* __restrict__ x,
                                            const float* __restrict__ w,
                                            const float* __restrict__ ow,
                                            u16* __restrict__ x16,
                                            u16* __restrict__ w16,
                                            u16* __restrict__ ow16) {
    int i = blockIdx.x * 256 + threadIdx.x;   // < 1048576
    const float* in; u16* out; int off;
    if (i < 524288)       { in = x;  out = x16;  off = i; }
    else if (i < 917504)  { in = w;  out = w16;  off = i - 524288; }
    else                  { in = ow; out = ow16; off = i - 917504; }
    const float4* p = (const float4*)(in + (size_t)off * 8);
    float4 a = p[0], b = p[1];
    u16x8 o;
    o[0] = f2bf(a.x); o[1] = f2bf(a.y); o[2] = f2bf(a.z); o[3] = f2bf(a.w);
    o[4] = f2bf(b.x); o[5] = f2bf(b.y); o[6] = f2bf(b.z); o[7] = f2bf(b.w);
    *(u16x8*)(out + (size_t)off * 8) = o;
}

// C[m][n] = sum_k A[m][k]*B[n][k]; A,B bf16 row-major; C fp32 or bf16 (template).
// 128x128 tile, 4 waves, BK=32, global_load_lds + 2-phase dbuf. 1-D grid,
// XCD-bijective swizzle (grid % 8 == 0), col tiles = nbx.
template<bool BF16OUT>
__global__ __launch_bounds__(256) void gemm128(const u16* __restrict__ A,
                                               const u16* __restrict__ B,
                                               void* __restrict__ Cv,
                                               int N, int K, int nbx) {
    __shared__ u16 As[2][4096];   // [128][32] linear, matches gload_lds lane order
    __shared__ u16 Bs[2][4096];
    const int tid = threadIdx.x, lane = tid & 63, wave = tid >> 6;
    const int cpx = gridDim.x >> 3;
    const int nid = (blockIdx.x & 7) * cpx + (blockIdx.x >> 3);
    const int m0 = (nid / nbx) << 7, n0 = (nid % nbx) << 7;
    const int wr = (wave >> 1) << 6, wc = (wave & 1) << 6;
    const int fr = lane & 15, fo = (lane >> 4) << 3;
    const int srow = tid >> 2, scol = (tid & 3) << 3;
    const u16* Ag = A + (size_t)(m0 + srow) * K + scol;
    const u16* Bg = B + (size_t)(n0 + srow) * K + scol;
    u16* AsW = &As[0][0] + (wave << 9);   // wave-uniform LDS base (+lane*16B by HW)
    u16* BsW = &Bs[0][0] + (wave << 9);
    f32x4 acc[4][4] = {};
    const int nsteps = K >> 5;
    glds16(Ag, AsW);
    glds16(Ag + (size_t)64 * K, AsW + 2048);
    glds16(Bg, BsW);
    glds16(Bg + (size_t)64 * K, BsW + 2048);
    int cur = 0;
    for (int s = 0; s < nsteps; ++s) {
        __syncthreads();   // buf[cur] staged (drains vmcnt), prev reads done
        if (s + 1 < nsteps) {
            const u16* Ap = Ag + (s + 1) * 32;
            const u16* Bp = Bg + (s + 1) * 32;
            const int nb = (cur ^ 1) << 12;
            glds16(Ap, AsW + nb);
            glds16(Ap + (size_t)64 * K, AsW + nb + 2048);
            glds16(Bp, BsW + nb);
            glds16(Bp + (size_t)64 * K, BsW + nb + 2048);
        }
        const u16* Ab = &As[cur][0];
        const u16* Bb = &Bs[cur][0];
        bf16x8 af[4], bfr[4];
        #pragma unroll
        for (int i = 0; i < 4; ++i)
            af[i] = *(const bf16x8*)(Ab + (wr + i * 16 + fr) * 32 + fo);
        #pragma unroll
        for (int i = 0; i < 4; ++i)
            bfr[i] = *(const bf16x8*)(Bb + (wc + i * 16 + fr) * 32 + fo);
        #pragma unroll
        for (int i = 0; i < 4; ++i)
            #pragma unroll
            for (int j = 0; j < 4; ++j)
                acc[i][j] = __builtin_amdgcn_mfma_f32_16x16x32_bf16(af[i], bfr[j], acc[i][j], 0, 0, 0);
        cur ^= 1;
    }
    const int cr = (lane >> 4) << 2, cc = lane & 15;
    if constexpr (BF16OUT) {
        u16* C = (u16*)Cv;
        #pragma unroll
        for (int i = 0; i < 4; ++i)
            for (int j = 0; j < 4; ++j)
                for (int r = 0; r < 4; ++r)
                    C[(size_t)(m0 + wr + i * 16 + cr + r) * N + (n0 + wc + j * 16 + cc)] =
                        f2bf(acc[i][j][r]);
    } else {
        float* C = (float*)Cv;
        #pragma unroll
        for (int i = 0; i < 4; ++i)
            for (int j = 0; j < 4; ++j)
                for (int r = 0; r < 4; ++r)
                    C[(size_t)(m0 + wr + i * 16 + cr + r) * N + (n0 + wc + j * 16 + cc)] =
                        acc[i][j][r];
    }
}

// Fused RoPE(Q,K) + V-transpose. blockIdx.x < 8192: rope path (as before);
// else vtrans path (idx-8192 decodes st/h/b). Branch is block-uniform.
__global__ __launch_bounds__(256) void rope_vt(const u16* __restrict__ qkv,
                                               const int* __restrict__ pos,
                                               u16* __restrict__ Qb,
                                               u16* __restrict__ Kb,
                                               u16* __restrict__ Vt) {
    __shared__ u16 lds[64][72];
    if (blockIdx.x < 8192) {
        int tid = blockIdx.x * 256 + threadIdx.x;   // 0 .. 2^21-1
        int t = tid & 31;
        int h = (tid >> 5) & 15;
        int s = (tid >> 9) & 2047;
        int b = tid >> 20;
        const u16* row = qkv + (size_t)((b << 11) + s) * 3072;
        float fp  = (float)pos[s];
        float inv = exp2f((float)t * -0.4152410118609203f);
        float rev = fp * inv * 0.15915494309189535f;
        rev = rev - floorf(rev);
        float sn = __builtin_amdgcn_sinf(rev);   // v_sin_f32: sin(2*pi*x)
        float cs = __builtin_amdgcn_cosf(rev);
        int off = h * 64 + 2 * t;
        u16x2 q2 = *(const u16x2*)(row + off);
        u16x2 k2 = *(const u16x2*)(row + 1024 + off);
        float qx = bf2f(q2[0]), qy = bf2f(q2[1]);
        float kx = bf2f(k2[0]), ky = bf2f(k2[1]);
        size_t oidx = (((size_t)(b * 16 + h) * 2048) + s) * 64 + 2 * t;
        const float qs = 0.18033688011112042f;   // 0.125 * log2(e)
        u16x2 qo, ko;
        qo[0] = f2bf((qx * cs - qy * sn) * qs);
        qo[1] = f2bf((qx * sn + qy * cs) * qs);
        ko[0] = f2bf(kx * cs - ky * sn);
        ko[1] = f2bf(ky * cs + kx * sn);
        *(u16x2*)&Qb[oidx] = qo;
        *(u16x2*)&Kb[oidx] = ko;
    } else {
        const int idx = blockIdx.x - 8192;       // 0..1023
        const int t = threadIdx.x;
        const int st = idx & 31, h = (idx >> 5) & 15, b = idx >> 9;
        const int s0 = st << 6;
        {
            const int r = t >> 2, c0 = (t & 3) << 4;
            const u16* src = qkv + (size_t)((b << 11) + s0 + r) * 3072 + 2048 + h * 64 + c0;
            *(u16x8*)&lds[r][c0]     = *(const u16x8*)src;
            *(u16x8*)&lds[r][c0 + 8] = *(const u16x8*)(src + 8);
        }
        __syncthreads();
        const size_t obase = ((size_t)((b << 4) + h) << 17) + (st << 6);
        #pragma unroll
        for (int w = 0; w < 2; ++w) {
            const int q = t + (w << 8);
            const int d = q >> 3, c = q & 7;
            u16x8 o;
            #pragma unroll
            for (int i = 0; i < 8; ++i) {
                const int p = (c << 3) + i;          // storage position 0..63
                const int k = ((p >> 5) << 5) + (((p >> 3) & 3) << 2) + (p & 3)
                            + (((p >> 2) & 1) << 4); // actual key
                o[i] = lds[k][d];
            }
            *(u16x8*)(Vt + obase + ((size_t)d << 11) + (c << 3)) = o;
        }
    }
}

// Causal flash attention, NO online max, IN-REGISTER P (swapped-operand QK^T).
// 512 blocks x 4 waves (256 thr); block = balanced pair (qt, 31-pr), 33 tiles.
// Wave (qsub, half): 32 q-rows (2 groups of 16) x 32 keys -> K/V LDS fragments
// read ONCE and used by both q-groups (halves LDS traffic vs 16q waves).
// 3-buffer counted-vmcnt pipeline (4 glds/wave/tile -> vmcnt(4)).
// l = sum_k P via ones-MFMA; halves combined via dedicated LDS buffer.
__global__ __launch_bounds__(256, 2) void attn_causal(const u16* __restrict__ Q,
                                                      const u16* __restrict__ K,
                                                      const u16* __restrict__ Vt,
                                                      u16* __restrict__ O) {
    __shared__ u16 smem[24576];  // 3 bufs x (K 4096 | V 4096) u16 = 48 KB
    __shared__ float cmb[5248];  // combine: [qsub][lane][41] (pad 41: conflict-free)
    const int tid = threadIdx.x, lane = tid & 63, wave = tid >> 6;   // wave 0..3
    const int nid = ((blockIdx.x & 7) << 6) + (blockIdx.x >> 3);     // XCD-contiguous
    const int pr = nid & 15, h = (nid >> 4) & 15, b = nid >> 8;
    const int S = 2048;
    const size_t base = (size_t)((b << 4) + h) << 17;   // (b*16+h)*2048*64
    const int fr = lane & 15, fo = (lane >> 4) << 3, cr = (lane >> 4) << 2;
    const int schk = lane & 7, srow8 = lane >> 3;
    const int qsub = wave >> 1, half = wave & 1;
    float* const slot = cmb + qsub * 2624 + lane * 41;
    u16x8 ones_u;
    #pragma unroll
    for (int i = 0; i < 8; ++i) ones_u[i] = 0x3F80;   // bf16 1.0
    const bf16x8 ones = as_bf16x8(ones_u);

    // stage tile t into buf bi: wave stages 16 K rows + 16 Vt rows (4 glds16),
    // source-swizzled global addresses, LDS linear (s8(r) = srow8 ^ (2w+g))
    auto stage = [&](int t, int bi) {
        #pragma unroll
        for (int g = 0; g < 2; ++g) {
            const int rg = (wave << 1) + g;              // 8-row group 0..7
            const int r  = (rg << 3) + srow8;
            const int ck = (schk ^ srow8 ^ rg) << 3;
            glds16(K  + base + ((size_t)((t << 6) + r) << 6) + ck,
                   &smem[bi * 8192 + (rg << 9)]);
            glds16(Vt + base + ((size_t)r << 11) + (t << 6) + ck,
                   &smem[bi * 8192 + 4096 + (rg << 9)]);
        }
    };

    for (int phase = 0; phase < 2; ++phase) {
        const int qt = phase ? (31 - pr) : pr;
        const int nkt = qt + 1;
        const int qw = (qt << 6) + (qsub << 5);          // wave's 32-q base
        bf16x8 aq[2][2];
        #pragma unroll
        for (int qg = 0; qg < 2; ++qg) {
            const u16* qrow = Q + base + (size_t)(qw + (qg << 4) + fr) * 64;
            aq[qg][0] = as_bf16x8(*(const u16x8*)(qrow + fo));
            aq[qg][1] = as_bf16x8(*(const u16x8*)(qrow + 32 + fo));
        }
        f32x4 oacc[2][4] = {};
        f32x4 lacc[2] = {};
        stage(0, 0);
        if (nkt > 1) stage(1, 1);
        int cur = 0;
        for (int t = 0; t < nkt; ++t) {
            // counted wait: newest 4 VMEM = tile t+1's stages (if any)
            if (t + 1 < nkt) asm volatile("s_waitcnt vmcnt(4)" ::: "memory");
            else             asm volatile("s_waitcnt vmcnt(0)" ::: "memory");
            __builtin_amdgcn_s_barrier();           // raw: no vmcnt drain
            __builtin_amdgcn_sched_barrier(0);      // pin: nothing crosses
            int nb = cur + 2; if (nb >= 3) nb -= 3;
            if (t + 2 < nkt) stage(t + 2, nb);
            const u16* Kb = smem + cur * 8192;
            const u16* Vb = smem + cur * 8192 + 4096;
            const bool diag = (t == nkt - 1);
            // swapped QK^T: read each K fragment ONCE, use for both q-groups
            f32x4 sacc[2][2];
            __builtin_amdgcn_s_setprio(1);
            #pragma unroll
            for (int ch = 0; ch < 2; ++ch) {
                const int r = ((half << 1) + ch) * 16 + fr;
                const int sw = swz(r);
                bf16x8 bk0 = *(const bf16x8*)&Kb[r * 64 + (fo ^ sw)];
                bf16x8 bk1 = *(const bf16x8*)&Kb[r * 64 + ((32 + fo) ^ sw)];
                #pragma unroll
                for (int qg = 0; qg < 2; ++qg) {
                    f32x4 sc = {};
                    sc = __builtin_amdgcn_mfma_f32_16x16x32_bf16(bk0, aq[qg][0], sc, 0, 0, 0);
                    sc = __builtin_amdgcn_mfma_f32_16x16x32_bf16(bk1, aq[qg][1], sc, 0, 0, 0);
                    sacc[qg][ch] = sc;
                }
            }
            __builtin_amdgcn_s_setprio(0);
            // exp2 -> in-register PV A-fragments (mask = value-select on diag)
            bf16x8 pa[2];
            #pragma unroll
            for (int qg = 0; qg < 2; ++qg) {
                const int qloc = (qsub << 5) + (qg << 4) + fr;
                #pragma unroll
                for (int ch = 0; ch < 2; ++ch) {
                    const int cglob = (half << 1) + ch;
                    #pragma unroll
                    for (int r = 0; r < 4; ++r) {
                        float e = exp2f(sacc[qg][ch][r]);
                        if (diag) {
                            const int kloc = (cglob << 4) + cr + r;
                            e = (kloc <= qloc) ? e : 0.f;
                        }
                        pa[qg][ch * 4 + r] = (__bf16)e;
                    }
                }
            }
            // PV + row-sums: read each V fragment ONCE, use for both q-groups
            __builtin_amdgcn_s_setprio(1);
            lacc[0] = __builtin_amdgcn_mfma_f32_16x16x32_bf16(pa[0], ones, lacc[0], 0, 0, 0);
            lacc[1] = __builtin_amdgcn_mfma_f32_16x16x32_bf16(pa[1], ones, lacc[1], 0, 0, 0);
            #pragma unroll
            for (int tt = 0; tt < 4; ++tt) {
                const int d = tt * 16 + fr;
                bf16x8 bv = *(const bf16x8*)&Vb[d * 64 + (((half << 5) + fo) ^ swz(d))];
                oacc[0][tt] = __builtin_amdgcn_mfma_f32_16x16x32_bf16(pa[0], bv, oacc[0][tt], 0, 0, 0);
                oacc[1][tt] = __builtin_amdgcn_mfma_f32_16x16x32_bf16(pa[1], bv, oacc[1][tt], 0, 0, 0);
            }
            __builtin_amdgcn_s_setprio(0);
            cur = (cur + 1 == 3) ? 0 : cur + 1;
        }
        // ---- combine halves (additive) via dedicated buffer + store ----
        __syncthreads();
        if (half) {
            #pragma unroll
            for (int qg = 0; qg < 2; ++qg) {
                #pragma unroll
                for (int tt = 0; tt < 4; ++tt)
                    *(f32x4*)(slot + (qg * 4 + tt) * 4) = oacc[qg][tt];
                *(f32x4*)(slot + 32 + qg * 4) = lacc[qg];
            }
        }
        __syncthreads();
        if (!half) {
            #pragma unroll
            for (int qg = 0; qg < 2; ++qg) {
                #pragma unroll
                for (int tt = 0; tt < 4; ++tt) oacc[qg][tt] += *(const f32x4*)(slot + (qg * 4 + tt) * 4);
                lacc[qg] += *(const f32x4*)(slot + 32 + qg * 4);
                f32x4 inv;
                #pragma unroll
                for (int j = 0; j < 4; ++j) inv[j] = 1.f / lacc[qg][j];
                #pragma unroll
                for (int tt = 0; tt < 4; ++tt)
                    for (int j = 0; j < 4; ++j)
                        O[(size_t)(b * S + qw + (qg << 4) + cr + j) * 1024 + h * 64 + tt * 16 + fr] =
                            f2bf(oacc[qg][tt][j] * inv[j]);
            }
        }
        __syncthreads();
    }
}

extern "C" void kernel_launch(void* const* d_in, const int* in_sizes, int n_in,
                              void* d_out, int out_size, void* d_ws, size_t ws_size,
                              hipStream_t stream) {
    const float* x     = (const float*)d_in[0];   // [2,2048,1024]
    const float* qkv_w = (const float*)d_in[1];   // [3072,1024]
    const float* out_w = (const float*)d_in[2];   // [1024,1024]
    const int*   pos   = (const int*)d_in[3];     // [2048]
    float* out = (float*)d_out;                   // [2,2048,1024] fp32

    char* ws = (char*)d_ws;
    u16* qkv16 = (u16*)ws;                           // 4096*3072*2 = 25165824 B
    u16* Qb    = (u16*)(ws + 25165824);              // 8388608 B
    u16* Kb    = (u16*)(ws + 33554432);              // 8388608 B
    u16* Vtg   = (u16*)(ws + 41943040);              // 8388608 B (transposed V)
    u16* x16   = (u16*)(ws + 50331648);              // 8388608 B (reused as att16)
    u16* att16 = (u16*)(ws + 50331648);
    u16* w16   = (u16*)(ws + 58720256);              // 6291456 B
    u16* ow16  = (u16*)(ws + 65011712);              // 2097152 B  (total 67108864)

    // 0) fused fp32 -> bf16 converts (one launch)
    cvt3<<<4096, 256, 0, stream>>>(x, qkv_w, out_w, x16, w16, ow16);
    // 1) qkv16 = x @ qkv_w^T (bf16 out): M=4096, N=3072, K=1024
    gemm128<true><<<768, 256, 0, stream>>>(x16, w16, (void*)qkv16, 3072, 1024, 24);
    // 2) fused RoPE Q,K + V transpose (one launch)
    rope_vt<<<9216, 256, 0, stream>>>(qkv16, pos, Qb, Kb, Vtg);
    // 3) causal flash attention: 512 blocks x 256 thr, 32qx32k waves
    attn_causal<<<512, 256, 0, stream>>>(Qb, Kb, Vtg, att16);
    // 4) out = att16 @ out_w^T (fp32 out): M=4096, N=1024, K=1024
    gemm128<false><<<256, 256, 0, stream>>>(att16, ow16, (void*)out, 1024, 1024, 8);
}